// Round 4
// baseline (1098.771 us; speedup 1.0000x reference)
//
#include <hip/hip_runtime.h>
#include <hip/hip_cooperative_groups.h>

namespace cg = cooperative_groups;

// ChildSumTreeLSTM on a static 4-ary heap tree.
// N=8192, H=256, D=300, K=4, OUT=4. Leaves = 2048..8191. Internal 0..2047, 7 levels.
// Workspace (50.3 MB):
//   gx : [8192][1024] f32   (gate order i,f,o,u)
//   Hb : [8192][256]  f32
//   Cb : [8192][256]  f32
// D (level-GEMM scratch, <=7.3 MB) aliases gx rows 2048.. (dead after leaf phase).

#define N_NODES 8192
#define HDIM 256
#define DDIM 300
#define GXC 1024
#define LEAF_FIRST 2048
#define WH_STRIDE 65536   // 256*256
#define NBLK 448          // cooperative grid: <=2 blocks/CU, co-resident

__device__ __forceinline__ float sigf(float x) { return 1.0f / (1.0f + __expf(-x)); }

// ---------- Kernel 1: gx[n][c] = emb[xs[n]] · Wx[c] + bx[c]  (64x64 tile) ----
__global__ __launch_bounds__(256) void gx_gemm(
    const int* __restrict__ xs, const float* __restrict__ emb,
    const float* __restrict__ Wx, const float* __restrict__ bx,
    float* __restrict__ gx)
{
    __shared__ __align__(16) float As[16][68];
    __shared__ __align__(16) float Bs[16][68];
    const int tid  = threadIdx.x;
    const int n0   = blockIdx.y * 64;
    const int c0   = blockIdx.x * 64;
    const int sr   = tid >> 2;
    const int sk   = (tid & 3) << 2;
    const int trow = (tid >> 4) << 2;
    const int tcol = (tid & 15) << 2;

    const long arow = (long)xs[n0 + sr] * DDIM;
    const long brow = (long)(c0 + sr) * DDIM;

    float acc[4][4] = {};

    for (int k0 = 0; k0 < DDIM; k0 += 16) {
        float4 av, bv;
        if (k0 + sk < DDIM) {
            av = *(const float4*)(emb + arow + k0 + sk);
            bv = *(const float4*)(Wx  + brow + k0 + sk);
        } else {
            av = make_float4(0.f, 0.f, 0.f, 0.f);
            bv = make_float4(0.f, 0.f, 0.f, 0.f);
        }
        __syncthreads();
        As[sk+0][sr] = av.x; As[sk+1][sr] = av.y; As[sk+2][sr] = av.z; As[sk+3][sr] = av.w;
        Bs[sk+0][sr] = bv.x; Bs[sk+1][sr] = bv.y; Bs[sk+2][sr] = bv.z; Bs[sk+3][sr] = bv.w;
        __syncthreads();
        #pragma unroll
        for (int k = 0; k < 16; k++) {
            float4 a = *(const float4*)&As[k][trow];
            float4 b = *(const float4*)&Bs[k][tcol];
            float avv[4] = {a.x, a.y, a.z, a.w};
            float bvv[4] = {b.x, b.y, b.z, b.w};
            #pragma unroll
            for (int i = 0; i < 4; i++)
                #pragma unroll
                for (int j = 0; j < 4; j++)
                    acc[i][j] = fmaf(avv[i], bvv[j], acc[i][j]);
        }
    }

    #pragma unroll
    for (int i = 0; i < 4; i++) {
        const int col = c0 + tcol;
        float4 r;
        r.x = acc[i][0] + bx[col + 0];
        r.y = acc[i][1] + bx[col + 1];
        r.z = acc[i][2] + bx[col + 2];
        r.w = acc[i][3] + bx[col + 3];
        *(float4*)(gx + (long)(n0 + trow + i) * GXC + col) = r;
    }
}

// ---------- Kernel 2: cooperative fused tree --------------------------------
// Phase 0: leaves. Then per level: Phase A (7-section GEMM into D), grid.sync,
// Phase B (pointwise combine -> h,c), grid.sync. Finally block 0: output.
__global__ __launch_bounds__(256) void tree_coop(
    const float* __restrict__ gx, const int* __restrict__ child_idx,
    const float* __restrict__ child_mask, const float* __restrict__ Wh,
    const float* __restrict__ bh, const float* __restrict__ Wout,
    const float* __restrict__ bout, float* __restrict__ Hb,
    float* __restrict__ Cb, float* __restrict__ D, float* __restrict__ out)
{
    cg::grid_group grid = cg::this_grid();
    const int bid = blockIdx.x;
    const int nB  = gridDim.x;
    const int tid = threadIdx.x;

    __shared__ __align__(16) float Xs[16][68];
    __shared__ __align__(16) float Ws[16][68];

    // ---- Phase 0: leaves (elementwise) ----
    for (int node = LEAF_FIRST + bid; node < N_NODES; node += nB) {
        const float* g = gx + (long)node * GXC;
        const float gi = g[tid]       + bh[tid];
        const float go = g[512 + tid] + bh[512 + tid];
        const float gu = g[768 + tid] + bh[768 + tid];
        const float c  = sigf(gi) * tanhf(gu);
        const float h  = sigf(go) * tanhf(c);
        Hb[(long)node * HDIM + tid] = h;
        Cb[(long)node * HDIM + tid] = c;
    }
    grid.sync();

    const int pf[7] = {1365, 341, 85, 21, 5, 1, 0};
    const int pc[7] = { 683, 1024, 256, 64, 16, 4, 1};

    for (int p = 0; p < 7; p++) {
        const int first = pf[p];
        const int M     = pc[p];
        const int tilesX = (M + 63) / 64;
        const int ntiles = tilesX * 7 * 4;

        // ---- Phase A: D[sec][nl][r] = Wh_g[r,:] · X[nl,:] ----
        for (int tile = bid; tile < ntiles; tile += nB) {
            const int tx   = tile % tilesX;
            const int rest = tile / tilesX;
            const int sec  = rest % 7;   // 0=i 1=o 2=u 3..6=f(child)
            const int rz   = rest / 7;   // 64-row tile of Wh_g
            const int c0   = tx * 64;
            const int r0   = rz * 64;
            const int sr   = tid >> 2;
            const int sk   = (tid & 3) << 2;
            const int trow = (tid >> 4) << 2;
            const int tcol = (tid & 15) << 2;

            const float* Wg;
            if      (sec == 0) Wg = Wh;                  // i
            else if (sec == 1) Wg = Wh + 2 * WH_STRIDE;  // o
            else if (sec == 2) Wg = Wh + 3 * WH_STRIDE;  // u
            else               Wg = Wh + 1 * WH_STRIDE;  // f

            const int  nl    = c0 + sr;
            const bool valid = nl < M;
            int   ci[4];
            float cm[4] = {0.f, 0.f, 0.f, 0.f};
            if (valid) {
                const int n = first + nl;
                if (sec < 3) {
                    #pragma unroll
                    for (int k = 0; k < 4; k++) {
                        ci[k] = child_idx[n * 4 + k];
                        cm[k] = child_mask[n * 4 + k];
                    }
                } else {
                    ci[0] = child_idx[n * 4 + (sec - 3)];
                    cm[0] = child_mask[n * 4 + (sec - 3)];
                }
            }
            const long wrow = (long)(r0 + sr) * HDIM;

            float acc[4][4] = {};

            for (int k0 = 0; k0 < HDIM; k0 += 16) {
                float4 xv = make_float4(0.f, 0.f, 0.f, 0.f);
                if (valid) {
                    if (sec < 3) {
                        #pragma unroll
                        for (int k = 0; k < 4; k++)
                            if (cm[k] != 0.f) {
                                const float4 hv = *(const float4*)(Hb + ci[k] * HDIM + k0 + sk);
                                xv.x += hv.x; xv.y += hv.y; xv.z += hv.z; xv.w += hv.w;
                            }
                    } else if (cm[0] != 0.f) {
                        xv = *(const float4*)(Hb + ci[0] * HDIM + k0 + sk);
                    }
                }
                const float4 wv = *(const float4*)(Wg + wrow + k0 + sk);
                __syncthreads();
                Xs[sk+0][sr] = xv.x; Xs[sk+1][sr] = xv.y; Xs[sk+2][sr] = xv.z; Xs[sk+3][sr] = xv.w;
                Ws[sk+0][sr] = wv.x; Ws[sk+1][sr] = wv.y; Ws[sk+2][sr] = wv.z; Ws[sk+3][sr] = wv.w;
                __syncthreads();
                #pragma unroll
                for (int k = 0; k < 16; k++) {
                    float4 a = *(const float4*)&Ws[k][trow];
                    float4 b = *(const float4*)&Xs[k][tcol];
                    float avv[4] = {a.x, a.y, a.z, a.w};
                    float bvv[4] = {b.x, b.y, b.z, b.w};
                    #pragma unroll
                    for (int i = 0; i < 4; i++)
                        #pragma unroll
                        for (int j = 0; j < 4; j++)
                            acc[i][j] = fmaf(avv[i], bvv[j], acc[i][j]);
                }
            }

            #pragma unroll
            for (int j = 0; j < 4; j++) {
                const int col = c0 + tcol + j;
                if (col < M) {
                    float4 r;
                    r.x = acc[0][j]; r.y = acc[1][j]; r.z = acc[2][j]; r.w = acc[3][j];
                    *(float4*)(D + ((long)(sec * M + col)) * HDIM + r0 + trow) = r;
                }
            }
        }
        grid.sync();

        // ---- Phase B: pointwise combine ----
        for (int nl = bid; nl < M; nl += nB) {
            const int n = first + nl;
            const float di = D[((long)(0 * M + nl)) * HDIM + tid];
            const float dO = D[((long)(1 * M + nl)) * HDIM + tid];
            const float du = D[((long)(2 * M + nl)) * HDIM + tid];
            const float* g = gx + (long)n * GXC;
            const float gi  = g[tid]       + bh[tid]       + di;
            const float gfb = g[256 + tid] + bh[256 + tid];
            const float go  = g[512 + tid] + bh[512 + tid] + dO;
            const float gu  = g[768 + tid] + bh[768 + tid] + du;

            float c = sigf(gi) * tanhf(gu);
            #pragma unroll
            for (int k = 0; k < 4; k++) {
                const float m = child_mask[n * 4 + k];
                if (m != 0.f) {
                    const float df = D[((long)((3 + k) * M + nl)) * HDIM + tid];
                    const float cc = Cb[(long)child_idx[n * 4 + k] * HDIM + tid];
                    c = fmaf(sigf(gfb + df), cc, c);
                }
            }
            const float h = sigf(go) * tanhf(c);
            Hb[(long)n * HDIM + tid] = h;
            Cb[(long)n * HDIM + tid] = c;
        }
        grid.sync();
    }

    // ---- Output phase: block 0 only ----
    if (bid == 0) {
        const int o    = tid >> 6;
        const int lane = tid & 63;
        float s = 0.f;
        for (int j = lane; j < HDIM; j += 64)
            s = fmaf(Wout[o * HDIM + j], Hb[j], s);
        #pragma unroll
        for (int off = 32; off > 0; off >>= 1)
            s += __shfl_down(s, off, 64);
        __shared__ float logits[4];
        if (lane == 0) logits[o] = s + bout[o];
        __syncthreads();
        if (tid == 0) {
            float m = logits[0];
            #pragma unroll
            for (int i = 1; i < 4; i++) m = fmaxf(m, logits[i]);
            float se = 0.f;
            #pragma unroll
            for (int i = 0; i < 4; i++) se += __expf(logits[i] - m);
            const float lse = m + __logf(se);
            #pragma unroll
            for (int i = 0; i < 4; i++) out[i] = logits[i] - lse;
        }
    }
}

extern "C" void kernel_launch(void* const* d_in, const int* in_sizes, int n_in,
                              void* d_out, int out_size, void* d_ws, size_t ws_size,
                              hipStream_t stream)
{
    const int*   xs         = (const int*)  d_in[0];
    const int*   child_idx  = (const int*)  d_in[1];
    const float* child_mask = (const float*)d_in[2];
    const float* emb        = (const float*)d_in[3];
    const float* Wx         = (const float*)d_in[4];
    const float* bx         = (const float*)d_in[5];
    const float* Wh         = (const float*)d_in[6];
    const float* bh         = (const float*)d_in[7];
    const float* Wout       = (const float*)d_in[8];
    const float* bout       = (const float*)d_in[9];
    float* out = (float*)d_out;

    float* gxb = (float*)d_ws;
    float* Hb  = gxb + (size_t)N_NODES * GXC;
    float* Cb  = Hb  + (size_t)N_NODES * HDIM;
    // D aliases gx rows of leaf nodes (dead after leaf phase).
    float* Dbuf = gxb + (size_t)LEAF_FIRST * GXC;

    gx_gemm<<<dim3(GXC / 64, N_NODES / 64), 256, 0, stream>>>(xs, emb, Wx, bx, gxb);

    void* args[] = {(void*)&gxb, (void*)&child_idx, (void*)&child_mask,
                    (void*)&Wh, (void*)&bh, (void*)&Wout, (void*)&bout,
                    (void*)&Hb, (void*)&Cb, (void*)&Dbuf, (void*)&out};
    hipLaunchCooperativeKernel((void*)tree_coop, dim3(NBLK), dim3(256),
                               args, 0, stream);
}

// Round 5
// 418.017 us; speedup vs baseline: 2.6285x; 2.6285x over previous
//
#include <hip/hip_runtime.h>

// ChildSumTreeLSTM on a static 4-ary heap tree.
// N=8192, H=256, D=300, K=4, OUT=4. Leaves = 2048..8191. Internal 0..2047, 7 levels.
// Key identity: children of level p form a contiguous range = previous level
// (∪ leaves). So per-child f-projections Wf·h_c become dense GEMMs over
// contiguous node ranges: F[n] = Wf·h_n, computed for leaves in one big
// parallel GEMM and for each level right after its h is produced.
// Workspace (50.3 MB):
//   gx : [8192][1024] f32   (gate order i,f,o,u)
//   Hb : [8192][256]  f32
//   Cb : [8192][256]  f32
// F ([8192][256], 8.4 MB) and D (3 MB) alias gx rows 2048.. (dead after leaves).

#define N_NODES 8192
#define HDIM 256
#define DDIM 300
#define GXC 1024
#define LEAF_FIRST 2048
#define WH_STRIDE 65536   // 256*256

__device__ __forceinline__ float sigf(float x) { return 1.0f / (1.0f + __expf(-x)); }

// ---------- Kernel 1: gx[n][c] = emb[xs[n]] · Wx[c] + bx[c]  (64x128 tile) ---
__global__ __launch_bounds__(256) void gx_gemm(
    const int* __restrict__ xs, const float* __restrict__ emb,
    const float* __restrict__ Wx, const float* __restrict__ bx,
    float* __restrict__ gx)
{
    __shared__ __align__(16) float As[16][68];    // [k][node]
    __shared__ __align__(16) float Bs[16][136];   // [k][col]
    const int tid  = threadIdx.x;
    const int n0   = blockIdx.y * 64;
    const int c0   = blockIdx.x * 128;
    const int ar   = tid >> 2;            // 0..63   A staging row
    const int ak   = (tid & 3) << 2;      // 0,4,8,12
    const int br   = tid >> 1;            // 0..127  B staging row
    const int bk   = (tid & 1) << 3;      // 0 or 8
    const int trow = (tid >> 4) << 2;     // 4-row group
    const int tcol = (tid & 15) << 3;     // 8-col group

    const long arow = (long)xs[n0 + ar] * DDIM;
    const long brow = (long)(c0 + br) * DDIM;

    float acc[4][8] = {};

    for (int k0 = 0; k0 < DDIM; k0 += 16) {
        float4 av  = make_float4(0.f, 0.f, 0.f, 0.f);
        float4 bv0 = av, bv1 = av;
        if (k0 + ak < DDIM)     av  = *(const float4*)(emb + arow + k0 + ak);
        if (k0 + bk < DDIM)     bv0 = *(const float4*)(Wx  + brow + k0 + bk);
        if (k0 + bk + 4 < DDIM) bv1 = *(const float4*)(Wx  + brow + k0 + bk + 4);
        __syncthreads();
        As[ak+0][ar] = av.x;  As[ak+1][ar] = av.y;  As[ak+2][ar] = av.z;  As[ak+3][ar] = av.w;
        Bs[bk+0][br] = bv0.x; Bs[bk+1][br] = bv0.y; Bs[bk+2][br] = bv0.z; Bs[bk+3][br] = bv0.w;
        Bs[bk+4][br] = bv1.x; Bs[bk+5][br] = bv1.y; Bs[bk+6][br] = bv1.z; Bs[bk+7][br] = bv1.w;
        __syncthreads();
        #pragma unroll
        for (int k = 0; k < 16; k++) {
            const float4 a  = *(const float4*)&As[k][trow];
            const float4 b0 = *(const float4*)&Bs[k][tcol];
            const float4 b1 = *(const float4*)&Bs[k][tcol + 4];
            const float avv[4] = {a.x, a.y, a.z, a.w};
            const float bvv[8] = {b0.x, b0.y, b0.z, b0.w, b1.x, b1.y, b1.z, b1.w};
            #pragma unroll
            for (int i = 0; i < 4; i++)
                #pragma unroll
                for (int j = 0; j < 8; j++)
                    acc[i][j] = fmaf(avv[i], bvv[j], acc[i][j]);
        }
    }

    const int col = c0 + tcol;
    const float4 bxa = *(const float4*)(bx + col);
    const float4 bxb = *(const float4*)(bx + col + 4);
    #pragma unroll
    for (int i = 0; i < 4; i++) {
        float4 r0, r1;
        r0.x = acc[i][0] + bxa.x; r0.y = acc[i][1] + bxa.y;
        r0.z = acc[i][2] + bxa.z; r0.w = acc[i][3] + bxa.w;
        r1.x = acc[i][4] + bxb.x; r1.y = acc[i][5] + bxb.y;
        r1.z = acc[i][6] + bxb.z; r1.w = acc[i][7] + bxb.w;
        float* dst = gx + (long)(n0 + trow + i) * GXC + col;
        *(float4*)dst = r0;
        *(float4*)(dst + 4) = r1;
    }
}

// ---------- Kernel 2: leaves — pure elementwise -----------------------------
__global__ __launch_bounds__(256) void leaf_kernel(
    const float* __restrict__ gx, const float* __restrict__ bh,
    float* __restrict__ Hb, float* __restrict__ Cb)
{
    const int node = LEAF_FIRST + blockIdx.x;
    const int t = threadIdx.x;
    const float* g = gx + (long)node * GXC;
    const float gi = g[t]       + bh[t];
    const float go = g[512 + t] + bh[512 + t];
    const float gu = g[768 + t] + bh[768 + t];
    const float c  = sigf(gi) * tanhf(gu);
    const float h  = sigf(go) * tanhf(c);
    Hb[(long)node * HDIM + t] = h;
    Cb[(long)node * HDIM + t] = c;
}

// ---------- Kernel 3: level GEMM ---------------------------------------------
// sec = secStart + blockIdx.y: 0=i, 1=o, 2=u (X = hs over [first,first+M)),
//                              3=f (X = Hb over [firstF, firstF+MF), contiguous).
// Output: sec<3 -> D[(sec*M+col)*256 + r];  sec==3 -> F[(firstF+col)*256 + r].
__global__ __launch_bounds__(256) void level_gemm(
    int first, int M, int firstF, int MF, int secStart,
    const float* __restrict__ Hb,
    const int* __restrict__ child_idx, const float* __restrict__ child_mask,
    const float* __restrict__ Wh, float* __restrict__ D, float* __restrict__ F)
{
    const int sec  = secStart + blockIdx.y;
    const int cols = (sec < 3) ? M : MF;
    const int c0   = blockIdx.x * 64;
    if (c0 >= cols) return;                       // block-uniform
    const int r0   = blockIdx.z * 64;

    __shared__ __align__(16) float Xs[16][68];
    __shared__ __align__(16) float Ws[16][68];
    const int tid  = threadIdx.x;
    const int sr   = tid >> 2;
    const int sk   = (tid & 3) << 2;
    const int trow = (tid >> 4) << 2;
    const int tcol = (tid & 15) << 2;

    const float* Wg;
    if      (sec == 0) Wg = Wh;                  // i
    else if (sec == 1) Wg = Wh + 2 * WH_STRIDE;  // o
    else if (sec == 2) Wg = Wh + 3 * WH_STRIDE;  // u
    else               Wg = Wh + 1 * WH_STRIDE;  // f

    const int  nl    = c0 + sr;
    const bool valid = nl < cols;
    int   ci[4];
    float cm[4] = {0.f, 0.f, 0.f, 0.f};
    if (valid && sec < 3) {
        const int n = first + nl;
        #pragma unroll
        for (int k = 0; k < 4; k++) {
            ci[k] = child_idx[n * 4 + k];
            cm[k] = child_mask[n * 4 + k];
        }
    }
    const long wrow = (long)(r0 + sr) * HDIM;
    const long frow = (long)(firstF + nl) * HDIM;

    float acc[4][4] = {};

    for (int k0 = 0; k0 < HDIM; k0 += 16) {
        float4 xv = make_float4(0.f, 0.f, 0.f, 0.f);
        if (valid) {
            if (sec < 3) {
                #pragma unroll
                for (int k = 0; k < 4; k++)
                    if (cm[k] != 0.f) {
                        const float4 hv = *(const float4*)(Hb + (long)ci[k] * HDIM + k0 + sk);
                        xv.x += hv.x; xv.y += hv.y; xv.z += hv.z; xv.w += hv.w;
                    }
            } else {
                xv = *(const float4*)(Hb + frow + k0 + sk);
            }
        }
        const float4 wv = *(const float4*)(Wg + wrow + k0 + sk);
        __syncthreads();
        Xs[sk+0][sr] = xv.x; Xs[sk+1][sr] = xv.y; Xs[sk+2][sr] = xv.z; Xs[sk+3][sr] = xv.w;
        Ws[sk+0][sr] = wv.x; Ws[sk+1][sr] = wv.y; Ws[sk+2][sr] = wv.z; Ws[sk+3][sr] = wv.w;
        __syncthreads();
        #pragma unroll
        for (int k = 0; k < 16; k++) {
            const float4 a = *(const float4*)&Ws[k][trow];
            const float4 b = *(const float4*)&Xs[k][tcol];
            const float avv[4] = {a.x, a.y, a.z, a.w};
            const float bvv[4] = {b.x, b.y, b.z, b.w};
            #pragma unroll
            for (int i = 0; i < 4; i++)
                #pragma unroll
                for (int j = 0; j < 4; j++)
                    acc[i][j] = fmaf(avv[i], bvv[j], acc[i][j]);
        }
    }

    #pragma unroll
    for (int j = 0; j < 4; j++) {
        const int col = c0 + tcol + j;
        if (col < cols) {
            float4 r;
            r.x = acc[0][j]; r.y = acc[1][j]; r.z = acc[2][j]; r.w = acc[3][j];
            if (sec < 3)
                *(float4*)(D + ((long)(sec * M + col)) * HDIM + r0 + trow) = r;
            else
                *(float4*)(F + ((long)(firstF + col)) * HDIM + r0 + trow) = r;
        }
    }
}

// ---------- Kernel 4: pointwise combine (+ fused root output) ---------------
__global__ __launch_bounds__(256) void level_pointwise(
    int first, int M, const float* __restrict__ gx, const float* __restrict__ D,
    const float* __restrict__ F, const int* __restrict__ child_idx,
    const float* __restrict__ child_mask, const float* __restrict__ bh,
    float* __restrict__ Hb, float* __restrict__ Cb,
    int doOut, const float* __restrict__ Wout, const float* __restrict__ bout,
    float* __restrict__ out)
{
    const int nl = blockIdx.x;
    const int n  = first + nl;
    const int t  = threadIdx.x;
    const float di = D[((long)(0 * M + nl)) * HDIM + t];
    const float dO = D[((long)(1 * M + nl)) * HDIM + t];
    const float du = D[((long)(2 * M + nl)) * HDIM + t];
    const float* g = gx + (long)n * GXC;
    const float gi  = g[t]       + bh[t]       + di;
    const float gfb = g[256 + t] + bh[256 + t];
    const float go  = g[512 + t] + bh[512 + t] + dO;
    const float gu  = g[768 + t] + bh[768 + t] + du;

    float c = sigf(gi) * tanhf(gu);
    #pragma unroll
    for (int k = 0; k < 4; k++) {
        const float m = child_mask[n * 4 + k];
        if (m != 0.f) {
            const int ci = child_idx[n * 4 + k];
            const float df = F[(long)ci * HDIM + t];
            const float cc = Cb[(long)ci * HDIM + t];
            c = fmaf(sigf(gfb + df), cc, c);
        }
    }
    const float h = sigf(go) * tanhf(c);
    Hb[(long)n * HDIM + t] = h;
    Cb[(long)n * HDIM + t] = c;

    if (doOut) {
        __shared__ float sh[HDIM];
        __shared__ float logits[4];
        sh[t] = h;
        __syncthreads();
        const int o    = t >> 6;
        const int lane = t & 63;
        float s = 0.f;
        for (int j = lane; j < HDIM; j += 64)
            s = fmaf(Wout[o * HDIM + j], sh[j], s);
        #pragma unroll
        for (int off = 32; off > 0; off >>= 1)
            s += __shfl_down(s, off, 64);
        if (lane == 0) logits[o] = s + bout[o];
        __syncthreads();
        if (t == 0) {
            float m = logits[0];
            #pragma unroll
            for (int i = 1; i < 4; i++) m = fmaxf(m, logits[i]);
            float se = 0.f;
            #pragma unroll
            for (int i = 0; i < 4; i++) se += __expf(logits[i] - m);
            const float lse = m + __logf(se);
            #pragma unroll
            for (int i = 0; i < 4; i++) out[i] = logits[i] - lse;
        }
    }
}

extern "C" void kernel_launch(void* const* d_in, const int* in_sizes, int n_in,
                              void* d_out, int out_size, void* d_ws, size_t ws_size,
                              hipStream_t stream)
{
    const int*   xs         = (const int*)  d_in[0];
    const int*   child_idx  = (const int*)  d_in[1];
    const float* child_mask = (const float*)d_in[2];
    const float* emb        = (const float*)d_in[3];
    const float* Wx         = (const float*)d_in[4];
    const float* bx         = (const float*)d_in[5];
    const float* Wh         = (const float*)d_in[6];
    const float* bh         = (const float*)d_in[7];
    const float* Wout       = (const float*)d_in[8];
    const float* bout       = (const float*)d_in[9];
    float* out = (float*)d_out;

    float* gxb = (float*)d_ws;                          // [8192][1024]
    float* Hb  = gxb + (size_t)N_NODES * GXC;           // [8192][256]
    float* Cb  = Hb  + (size_t)N_NODES * HDIM;          // [8192][256]
    // F and D alias the leaf rows of gx (dead after leaf_kernel):
    float* Fbuf = gxb + (size_t)LEAF_FIRST * GXC;               // [8192][256] = 8.4 MB
    float* Dbuf = Fbuf + (size_t)N_NODES * HDIM;                // 3*1024*256  = 3.1 MB

    gx_gemm<<<dim3(GXC / 128, N_NODES / 64), 256, 0, stream>>>(xs, emb, Wx, bx, gxb);
    leaf_kernel<<<N_NODES - LEAF_FIRST, 256, 0, stream>>>(gxb, bh, Hb, Cb);

    // Big parallel GEMM: F[n] = Wf @ h_n for all 6144 leaves.
    level_gemm<<<dim3(96, 1, 4), 256, 0, stream>>>(
        0, 0, LEAF_FIRST, N_NODES - LEAF_FIRST, 3,
        Hb, child_idx, child_mask, Wh, Dbuf, Fbuf);

    const int pf[7] = {1365, 341, 85, 21, 5, 1, 0};
    const int pc[7] = { 683, 1024, 256, 64, 16, 4, 1};
    for (int p = 0; p < 7; p++) {
        const int M      = pc[p];
        const int first  = pf[p];
        const int MF     = (p == 0) ? 0 : pc[p - 1];
        const int firstF = (p == 0) ? 0 : pf[p - 1];
        const int tilesM = (M + 63) / 64;
        const int tilesF = (MF + 63) / 64;
        const int tilesX = tilesM > tilesF ? tilesM : tilesF;
        const int nsec   = (p == 0) ? 3 : 4;
        level_gemm<<<dim3(tilesX, nsec, 4), 256, 0, stream>>>(
            first, M, firstF, MF, 0,
            Hb, child_idx, child_mask, Wh, Dbuf, Fbuf);
        level_pointwise<<<M, 256, 0, stream>>>(
            first, M, gxb, Dbuf, Fbuf, child_idx, child_mask, bh, Hb, Cb,
            (p == 6) ? 1 : 0, Wout, bout, out);
    }
}